// Round 7
// baseline (192.479 us; speedup 1.0000x reference)
//
#include <hip/hip_runtime.h>

#define N_NODES 50000
#define D_NB 16
#define IN_DIM 256
#define OUT_DIM 128
#define K_HEADS 4
#define SLOPE 0.01f
#define NSLICE 16       // slice s = k*4 + cb; 32 cols each
#define SLICE_COLS 32

typedef __attribute__((ext_vector_type(8))) short short8;
typedef __attribute__((ext_vector_type(4))) float f32x4;

static __device__ __forceinline__ unsigned short f2bf(float f) {
    unsigned u = __float_as_uint(f);
    unsigned r = u + 0x7fffu + ((u >> 16) & 1u);   // RNE
    return (unsigned short)(r >> 16);
}
static __device__ __forceinline__ float bf2f(unsigned short b) {
    return __uint_as_float(((unsigned)b) << 16);
}

// ---------------- Kernel 0: W (f32) -> Wb (bf16), same [K][OUT][IN] layout ----------------
__global__ void wb_kernel(const float* __restrict__ W, unsigned short* __restrict__ Wb) {
    int id = blockIdx.x * blockDim.x + threadIdx.x;
    if (id < K_HEADS * OUT_DIM * IN_DIM) Wb[id] = f2bf(W[id]);
}

// ---------------- Kernel 1: MFMA GEMM, 64 rows/block, 16 x 16KB double-buffered stages ----------
// Stage st = (head k = st>>2, col-block cb = st&3): rows [k*128+cb*32, +32) of Wb = contiguous
// 16KB block. STAGE(st+1) issued before compute(st); one __syncthreads per stage (its implicit
// vmcnt(0) drains the prefetch). Output goes to slice layout Whb2[s][n][32] with s == st.
__global__ __launch_bounds__(256) void gemm_kernel(
    const float* __restrict__ X, const unsigned short* __restrict__ Wb,
    const float* __restrict__ a,
    unsigned short* __restrict__ Whb2, float* __restrict__ e_nb, float* __restrict__ e_self)
{
    __shared__ unsigned short Wlds[2][SLICE_COLS * IN_DIM];   // 2 x 16 KB

    const int t = threadIdx.x;
    const int lane = t & 63;
    const int w = t >> 6;
    const int lrow = lane & 15;
    const int lk = lane >> 4;
    const int m0 = blockIdx.x * 64 + w * 16;

    const int arow = m0 + lrow;
    const bool avalid = arow < N_NODES;

    // ---- A fragments (X rows, bf16), resident for whole kernel ----
    const float* Xr = X + (size_t)arow * IN_DIM + lk * 8;
    short8 af[8];
    #pragma unroll
    for (int kk = 0; kk < 8; ++kk) {
        short8 s;
        if (avalid) {
            float4 x0 = *(const float4*)(Xr + kk * 32);
            float4 x1 = *(const float4*)(Xr + kk * 32 + 4);
            s[0] = (short)f2bf(x0.x); s[1] = (short)f2bf(x0.y);
            s[2] = (short)f2bf(x0.z); s[3] = (short)f2bf(x0.w);
            s[4] = (short)f2bf(x1.x); s[5] = (short)f2bf(x1.y);
            s[6] = (short)f2bf(x1.z); s[7] = (short)f2bf(x1.w);
        } else {
            s = short8{0, 0, 0, 0, 0, 0, 0, 0};
        }
        af[kk] = s;
    }

    // ---- stage: 32 cols x 256 in = 1024 16B-chunks; 4 per thread; swizzled source ----
    auto STAGE = [&](int st, int buf) {
        const unsigned short* WbS = Wb + (size_t)st * SLICE_COLS * IN_DIM;
        #pragma unroll
        for (int i = 0; i < 4; ++i) {
            const int c = i * 256 + t;       // chunk id
            const int r = c >> 5;            // col-row (32 chunks/row)
            const int p = c & 31;            // linear LDS chunk pos
            const int cu = p ^ (r & 7);      // pre-swizzled source chunk
            const unsigned short* gsrc = WbS + r * IN_DIM + cu * 8;
            unsigned short* ldst = &Wlds[buf][c * 8];
            __builtin_amdgcn_global_load_lds(
                (const __attribute__((address_space(1))) void*)gsrc,
                (__attribute__((address_space(3))) void*)ldst, 16, 0, 0);
        }
    };

    float pnb = 0.f, psf = 0.f;
    STAGE(0, 0);
    __syncthreads();

    for (int st = 0; st < NSLICE; ++st) {
        const int buf = st & 1;
        if (st + 1 < NSLICE) STAGE(st + 1, buf ^ 1);

        f32x4 acc[2] = {};
        #pragma unroll
        for (int kk = 0; kk < 8; ++kk) {
            #pragma unroll
            for (int nt = 0; nt < 2; ++nt) {
                const int row = nt * 16 + lrow;
                const int pos = (kk * 4 + lk) ^ (row & 7);
                const short8 bf = *(const short8*)(&Wlds[buf][row * IN_DIM + pos * 8]);
                acc[nt] = __builtin_amdgcn_mfma_f32_16x16x32_bf16(bf, af[kk], acc[nt], 0, 0, 0);
            }
        }

        // epilogue: lane holds cols cb*32 + nt*16 + lk*4 .. +3 of head k, for X-row arow
        const int k = st >> 2, cb = st & 3;
        #pragma unroll
        for (int nt = 0; nt < 2; ++nt) {
            const float4 anb = *(const float4*)(a + k * 2 * OUT_DIM + cb * 32 + nt * 16 + lk * 4);
            const float4 asf = *(const float4*)(a + k * 2 * OUT_DIM + OUT_DIM + cb * 32 + nt * 16 + lk * 4);
            pnb += acc[nt][0] * anb.x + acc[nt][1] * anb.y
                 + acc[nt][2] * anb.z + acc[nt][3] * anb.w;
            psf += acc[nt][0] * asf.x + acc[nt][1] * asf.y
                 + acc[nt][2] * asf.z + acc[nt][3] * asf.w;
            if (avalid) {
                uint2 pk;
                pk.x = (unsigned)f2bf(acc[nt][0]) | ((unsigned)f2bf(acc[nt][1]) << 16);
                pk.y = (unsigned)f2bf(acc[nt][2]) | ((unsigned)f2bf(acc[nt][3]) << 16);
                *(uint2*)(Whb2 + ((size_t)st * N_NODES + arow) * SLICE_COLS + nt * 16 + lk * 4) = pk;
            }
        }
        if ((st & 3) == 3) {   // head complete: reduce e partials
            pnb += __shfl_xor(pnb, 16); pnb += __shfl_xor(pnb, 32);
            psf += __shfl_xor(psf, 16); psf += __shfl_xor(psf, 32);
            if (avalid && lane < 16) {
                e_nb[(size_t)arow * K_HEADS + k] = pnb;
                e_self[(size_t)arow * K_HEADS + k] = psf;
            }
            pnb = 0.f; psf = 0.f;
        }
        __syncthreads();
    }
}

// ---------------- Kernel 2: XCD-sliced gather + softmax + aggregate ----------------
// XCD x (blockIdx&7) owns slices {2x, 2x+1} (same head k = x>>1): 6.4 MB, L2-resident.
// 16 lanes per node: lane d = softmax slot AND col-pair d within each 32-col slice.
__global__ __launch_bounds__(256) void attn_kernel(
    const int* __restrict__ nidx, const unsigned short* __restrict__ Whb2,
    const float* __restrict__ e_nb, const float* __restrict__ e_self,
    float* __restrict__ out)
{
    const int xcd = blockIdx.x & 7;
    const int slot = blockIdx.x >> 3;       // 0..127
    const int w = threadIdx.x >> 6;
    const int lane = threadIdx.x & 63;
    const int nl = lane >> 4;               // node within wave (0..3)
    const int d = lane & 15;
    const int s0 = xcd * 2;
    const int k = s0 >> 2;                  // head
    const int cb0 = s0 & 3;                 // col-block of slice s0
    const unsigned short* S0 = Whb2 + (size_t)s0 * N_NODES * SLICE_COLS;
    const unsigned short* S1 = S0 + (size_t)N_NODES * SLICE_COLS;

    for (int i = slot; i < N_NODES / 16; i += 128) {
        const int n = i * 16 + w * 4 + nl;

        const int nbr = nidx[(size_t)n * D_NB + d];
        const float x = e_nb[(size_t)nbr * K_HEADS + k] + e_self[(size_t)n * K_HEADS + k];
        const float v = x > 0.f ? x : SLOPE * x;
        float m = v;
        #pragma unroll
        for (int s = 8; s >= 1; s >>= 1) m = fmaxf(m, __shfl_xor(m, s, 16));
        const float p = __expf(v - m);
        float sum = p;
        #pragma unroll
        for (int s = 8; s >= 1; s >>= 1) sum += __shfl_xor(sum, s, 16);
        const float alpha = p / sum;

        float a0 = 0.f, a1 = 0.f, a2 = 0.f, a3 = 0.f;
        #pragma unroll
        for (int dd = 0; dd < D_NB; ++dd) {
            const int src = (lane & 48) | dd;
            const float ad = __shfl(alpha, src);
            const int nd = __shfl(nbr, src);
            const unsigned u0 = *(const unsigned*)(S0 + (size_t)nd * SLICE_COLS + d * 2);
            const unsigned u1 = *(const unsigned*)(S1 + (size_t)nd * SLICE_COLS + d * 2);
            a0 += ad * bf2f((unsigned short)(u0 & 0xffffu));
            a1 += ad * bf2f((unsigned short)(u0 >> 16));
            a2 += ad * bf2f((unsigned short)(u1 & 0xffffu));
            a3 += ad * bf2f((unsigned short)(u1 >> 16));
        }
        float* op = out + (size_t)n * (K_HEADS * OUT_DIM) + k * OUT_DIM + cb0 * SLICE_COLS + d * 2;
        *(float2*)op        = float2{a0, a1};
        *(float2*)(op + 32) = float2{a2, a3};
    }
}

// ---------------- launch ----------------
extern "C" void kernel_launch(void* const* d_in, const int* in_sizes, int n_in,
                              void* d_out, int out_size, void* d_ws, size_t ws_size,
                              hipStream_t stream) {
    const float* X = (const float*)d_in[0];
    const float* W = (const float*)d_in[1];
    const float* a = (const float*)d_in[2];
    const int* nidx = (const int*)d_in[3];
    float* out = (float*)d_out;

    char* p = (char*)d_ws;
    unsigned short* Wb = (unsigned short*)p;      p += (size_t)K_HEADS * OUT_DIM * IN_DIM * 2;
    unsigned short* Whb2 = (unsigned short*)p;    p += (size_t)NSLICE * N_NODES * SLICE_COLS * 2;
    float* enb = (float*)p;                       p += (size_t)N_NODES * K_HEADS * 4;
    float* eself = (float*)p;

    hipLaunchKernelGGL(wb_kernel,
        dim3((K_HEADS * OUT_DIM * IN_DIM + 255) / 256), dim3(256), 0, stream, W, Wb);

    hipLaunchKernelGGL(gemm_kernel,
        dim3((N_NODES + 63) / 64), dim3(256), 0, stream, X, Wb, a, Whb2, enb, eself);

    hipLaunchKernelGGL(attn_kernel,
        dim3(8 * 128), dim3(256), 0, stream, nidx, Whb2, enb, eself, out);
}